// Round 8
// baseline (104.870 us; speedup 1.0000x reference)
//
#include <hip/hip_runtime.h>
#include <math.h>

#define BLOCK 256
#define RPB (BLOCK / 64)   // rows per block (one wave per row)

typedef float f32x4 __attribute__((ext_vector_type(4)));

__device__ __forceinline__ float sp(float x) {
    // softplus: max(x,0) + log(1 + exp(-|x|)) — fast intrinsics, huge error budget
    return fmaxf(x, 0.0f) + __logf(1.0f + __expf(-fabsf(x)));
}

// Wave64 inclusive scan (add) on the VALU via DPP (verified round 7).
__device__ __forceinline__ float wave_scan_f32(float s) {
    s += __int_as_float(__builtin_amdgcn_update_dpp(0, __float_as_int(s), 0x111, 0xf, 0xf, false));
    s += __int_as_float(__builtin_amdgcn_update_dpp(0, __float_as_int(s), 0x112, 0xf, 0xf, false));
    s += __int_as_float(__builtin_amdgcn_update_dpp(0, __float_as_int(s), 0x114, 0xf, 0xf, false));
    s += __int_as_float(__builtin_amdgcn_update_dpp(0, __float_as_int(s), 0x118, 0xf, 0xf, false));
    s += __int_as_float(__builtin_amdgcn_update_dpp(0, __float_as_int(s), 0x142, 0xa, 0xf, false));
    s += __int_as_float(__builtin_amdgcn_update_dpp(0, __float_as_int(s), 0x143, 0xc, 0xf, false));
    return s;
}

// wf_sl1: lane i <- lane i+1 (lane 63 <- 0; caller patches it)
__device__ __forceinline__ float shl1(float v) {
    return __int_as_float(__builtin_amdgcn_update_dpp(0, __float_as_int(v), 0x130, 0xf, 0xf, false));
}

__device__ __forceinline__ float bcast(float v, int lane) {
    return __int_as_float(__builtin_amdgcn_readlane(__float_as_int(v), lane));
}

__global__ __launch_bounds__(BLOCK) void socnet_kernel(
    const f32x4* __restrict__ X,      // (N, L) of 4-ch float4
    const float*  __restrict__ SC,    // (N, 4)
    const float*  __restrict__ wi1, const float* __restrict__ bi1,
    const float*  __restrict__ wi2, const float* __restrict__ bi2,
    const float*  __restrict__ we1, const float* __restrict__ be1,
    const float*  __restrict__ we2, const float* __restrict__ be2,
    f32x4* __restrict__ Y, int L)
{
    const int lane = threadIdx.x & 63;
    const int wid  = threadIdx.x >> 6;
    const int row  = blockIdx.x * RPB + wid;   // one wave per row

    const size_t rowoff = (size_t)row * (size_t)L;
    const f32x4* Xr = X + rowoff;
    f32x4*       Yr = Y + rowoff;

    // eta MLP weights (broadcast scalars)
    const float W10 = we1[0], W11 = we1[1], B1 = be1[0];
    const float W2  = we2[0], B2e = be2[0];

    // per-row scalars (wave-uniform)
    const float Q    = SC[row * 4 + 0];
    const float eta0 = SC[row * 4 + 1];
    const float R    = SC[row * 4 + 2];
    const float S3   = SC[row * 4 + 3];
    const float inv  = eta0 / (3600.0f * Q);

    // soc_init from X[row,0,:]
    const f32x4 x0 = Xr[0];
    const float h0 = sp(wi1[0] * x0.y + wi1[1] * x0.z + wi1[2] * x0.w + wi1[3] * R + bi1[0]);
    const float soc = S3 * (1.0f + (wi2[0] * h0 + bi2[0]));

    const int Lm1    = L - 1;
    const int ntiles = L >> 6;   // 64-element chunks

    // ---- depth-2 software pipeline (no barriers anywhere -> loads stay in flight) ----
    int i0 = lane;            if (i0 > Lm1) i0 = Lm1;
    int i1 = 64 + lane;       if (i1 > Lm1) i1 = Lm1;
    int i2 = 128 + lane;      if (i2 > Lm1) i2 = Lm1;
    f32x4 xa = Xr[i0];        // current chunk
    f32x4 xb = Xr[i1];        // next chunk (arrived by use-time)
    f32x4 xf = Xr[i2];        // in flight

    float de_a = W2 * sp(W10 * xa.y + W11 * xa.z + B1) + B2e;

    // carry starts at soc: y[p] = carry + (scan_incl - inc)
    f32x4 carry = (f32x4)(soc);

    for (int it = 0; it < ntiles; ++it) {
        // issue chunk it+3 (stays outstanding across iterations; nothing drains vmcnt)
        int ip = ((it + 3) << 6) + lane;
        if (ip > Lm1) ip = Lm1;
        const f32x4 xf2 = Xr[ip];

        // softplus for the NEXT chunk (one sp chain per element total)
        const float de_b = W2 * sp(W10 * xb.y + W11 * xb.z + B1) + B2e;

        // neighbor obs via DPP shift; lane 63 patched from next chunk's lane 0
        const bool last = (lane == 63);
        float ny = shl1(xa.y); if (last) ny = bcast(xb.y, 0);
        float nz = shl1(xa.z); if (last) nz = bcast(xb.z, 0);
        float nw = shl1(xa.w); if (last) nw = bcast(xb.w, 0);
        float nd = shl1(de_a); if (last) nd = bcast(de_b, 0);

        const float dy = inv * (1.0f + de_a) * xa.y;

        f32x4 inc;
        inc.x = (ny - xa.y) * dy;
        inc.y = (nz - xa.z) * dy;
        inc.z = (nw - xa.w) * dy;
        inc.w = (nd - de_a) * dy;

        // wave-inclusive scan, 4 fp32 channels, all on the VALU
        f32x4 scn;
        scn.x = wave_scan_f32(inc.x);
        scn.y = wave_scan_f32(inc.y);
        scn.z = wave_scan_f32(inc.z);
        scn.w = wave_scan_f32(inc.w);

        // y[p] = carry + exclusive prefix
        const f32x4 yv = carry + scn - inc;
        __builtin_nontemporal_store(yv, &Yr[(it << 6) + lane]);

        // carry += chunk total (lane 63 of inclusive scan), wave-uniform
        carry.x += bcast(scn.x, 63);
        carry.y += bcast(scn.y, 63);
        carry.z += bcast(scn.z, 63);
        carry.w += bcast(scn.w, 63);

        // rotate pipeline
        xa = xb; de_a = de_b;
        xb = xf;
        xf = xf2;
    }
}

extern "C" void kernel_launch(void* const* d_in, const int* in_sizes, int n_in,
                              void* d_out, int out_size, void* d_ws, size_t ws_size,
                              hipStream_t stream) {
    const f32x4* X   = (const f32x4*)d_in[0];
    const float* SC  = (const float*)d_in[1];
    const float* wi1 = (const float*)d_in[2];
    const float* bi1 = (const float*)d_in[3];
    const float* wi2 = (const float*)d_in[4];
    const float* bi2 = (const float*)d_in[5];
    const float* we1 = (const float*)d_in[6];
    const float* be1 = (const float*)d_in[7];
    const float* we2 = (const float*)d_in[8];
    const float* be2 = (const float*)d_in[9];
    f32x4* Y = (f32x4*)d_out;

    const int N = in_sizes[1] / 4;           // SC is (N,4)
    const int L = in_sizes[0] / (4 * N);     // X is (N,L,4)

    socnet_kernel<<<N / RPB, BLOCK, 0, stream>>>(X, SC, wi1, bi1, wi2, bi2,
                                                 we1, be1, we2, be2, Y, L);
}